// Round 2
// baseline (536.846 us; speedup 1.0000x reference)
//
#include <hip/hip_runtime.h>
#include <hip/hip_bf16.h>

#define Bdim 4
#define Tdim 2048
#define Wdim 1024
#define Kdim 7
#define Gdim 8
#define Cg   128
#define Hdim 64   // W / SE_R

// ---------------- K0: transpose conv_w [G][O][C][K] -> Wt [G][K][C][O] ----------------
__global__ __launch_bounds__(256) void k_wt(const float* __restrict__ conv_w,
                                            float* __restrict__ Wt) {
    int i = blockIdx.x * 256 + threadIdx.x;
    if (i >= Gdim * Kdim * Cg * Cg) return;
    int o = i & 127;
    int c = (i >> 7) & 127;
    int r = i >> 14;          // g*K + k
    int k = r % Kdim;
    int g = r / Kdim;
    Wt[i] = conv_w[(((size_t)(g * Cg + o)) * Cg + c) * Kdim + k];
}

// ---------------- K1: offsets = h @ offset_w + offset_b; -> p0, frac ----------------
__global__ __launch_bounds__(256) void k_offsets(const float* __restrict__ h,
                                                 const float* __restrict__ offset_w,
                                                 const float* __restrict__ offset_b,
                                                 int* __restrict__ p0a,
                                                 float* __restrict__ fra) {
    int bt = blockIdx.x;               // b*T + t
    int t = bt & (Tdim - 1);
    int tid = threadIdx.x;
    const float* row = h + (size_t)bt * Wdim;
    float4 hv = *(const float4*)(row + tid * 4);
    const float* ow = offset_w + (size_t)tid * 4 * Kdim;
    float acc[Kdim];
#pragma unroll
    for (int k = 0; k < Kdim; k++)
        acc[k] = hv.x * ow[k] + hv.y * ow[Kdim + k] + hv.z * ow[2 * Kdim + k] + hv.w * ow[3 * Kdim + k];

    __shared__ float wred[4][Kdim];
    int lane = tid & 63, wv = tid >> 6;
#pragma unroll
    for (int k = 0; k < Kdim; k++) {
        float v = acc[k];
#pragma unroll
        for (int off = 32; off > 0; off >>= 1) v += __shfl_down(v, off);
        if (lane == 0) wred[wv][k] = v;
    }
    __syncthreads();
    if (tid < Kdim) {
        float o = wred[0][tid] + wred[1][tid] + wred[2][tid] + wred[3][tid] + offset_b[tid];
        float base = (float)t + (float)(tid - 3);
        float pos = fminf(fmaxf(base + o, 0.f), (float)(Tdim - 1));
        float p0f = floorf(pos);
        p0a[bt * Kdim + tid] = (int)p0f;
        fra[bt * Kdim + tid] = pos - p0f;
    }
}

// ---------------- K2: deformable grouped conv (fp32 GEMM) ----------------
// block = (b, t-tile of 16, g); 256 threads; per-thread 4o x 2t accumulators
__global__ __launch_bounds__(256) void k_conv(const float* __restrict__ h,
                                              const float* __restrict__ Wt,
                                              const float* __restrict__ conv_b,
                                              const int* __restrict__ p0a,
                                              const float* __restrict__ fra,
                                              float* __restrict__ y) {
    int blk = blockIdx.x;              // ((b*128 + tc)*8 + g)
    int g = blk & 7;
    int tc = (blk >> 3) & 127;
    int b = blk >> 10;
    int t0 = tc * 16;

    __shared__ float samp[16][Kdim][Cg];   // 57,344 B
    int tid = threadIdx.x;
    int c = tid & 127;
    const float* hb = h + ((size_t)b * Tdim) * Wdim + g * Cg + c;
    for (int pr = tid >> 7; pr < 16 * Kdim; pr += 2) {
        int tt = pr / Kdim, k = pr - tt * Kdim;
        int idx = (b * Tdim + t0 + tt) * Kdim + k;
        int p0 = p0a[idx];
        float f = fra[idx];
        int p1 = min(p0 + 1, Tdim - 1);
        float v0 = hb[(size_t)p0 * Wdim];
        float v1 = hb[(size_t)p1 * Wdim];
        samp[tt][k][c] = v0 * (1.f - f) + v1 * f;
    }
    __syncthreads();

    int o4 = (tid & 31) * 4;
    int tq = tid >> 5;                 // 0..7
    int ta = tq * 2;
    float4 a0 = {0, 0, 0, 0}, a1 = {0, 0, 0, 0};
    const float* wg = Wt + (size_t)g * Kdim * Cg * Cg + o4;
#pragma unroll 1
    for (int k = 0; k < Kdim; k++) {
        const float* wk = wg + k * Cg * Cg;
        const float* s0 = &samp[ta][k][0];
        const float* s1 = &samp[ta + 1][k][0];
#pragma unroll 8
        for (int c2 = 0; c2 < Cg; c2++) {
            float4 w = *(const float4*)(wk + c2 * Cg);
            float sa = s0[c2], sb = s1[c2];
            a0.x += sa * w.x; a0.y += sa * w.y; a0.z += sa * w.z; a0.w += sa * w.w;
            a1.x += sb * w.x; a1.y += sb * w.y; a1.z += sb * w.z; a1.w += sb * w.w;
        }
    }
    float4 bb = *(const float4*)(conv_b + g * Cg + o4);
    a0.x += bb.x; a0.y += bb.y; a0.z += bb.z; a0.w += bb.w;
    a1.x += bb.x; a1.y += bb.y; a1.z += bb.z; a1.w += bb.w;
    float* yr = y + ((size_t)(b * Tdim + t0 + ta)) * Wdim + g * Cg + o4;
    *(float4*)yr = a0;
    *(float4*)(yr + Wdim) = a1;
}

// ---------------- K3: LayerNorm in-place ----------------
__global__ __launch_bounds__(256) void k_ln(float* __restrict__ y,
                                            const float* __restrict__ ln_g,
                                            const float* __restrict__ ln_b) {
    int bt = blockIdx.x;
    float* row = y + (size_t)bt * Wdim;
    int tid = threadIdx.x;
    float4 v = *(const float4*)(row + tid * 4);
    float s = v.x + v.y + v.z + v.w;
    float q = v.x * v.x + v.y * v.y + v.z * v.z + v.w * v.w;
    __shared__ float rs[4], rq[4];
    __shared__ float mu_s, inv_s;
    int lane = tid & 63, wv = tid >> 6;
#pragma unroll
    for (int off = 32; off > 0; off >>= 1) { s += __shfl_down(s, off); q += __shfl_down(q, off); }
    if (lane == 0) { rs[wv] = s; rq[wv] = q; }
    __syncthreads();
    if (tid == 0) {
        float S = rs[0] + rs[1] + rs[2] + rs[3];
        float Q = rq[0] + rq[1] + rq[2] + rq[3];
        float mu = S * (1.f / Wdim);
        float var = Q * (1.f / Wdim) - mu * mu;
        mu_s = mu;
        inv_s = rsqrtf(var + 1e-5f);
    }
    __syncthreads();
    float mu = mu_s, inv = inv_s;
    float4 gg = *(const float4*)(ln_g + tid * 4);
    float4 bb = *(const float4*)(ln_b + tid * 4);
    v.x = (v.x - mu) * inv * gg.x + bb.x;
    v.y = (v.y - mu) * inv * gg.y + bb.y;
    v.z = (v.z - mu) * inv * gg.z + bb.z;
    v.w = (v.w - mu) * inv * gg.w + bb.w;
    *(float4*)(row + tid * 4) = v;
}

// ---------------- K4a: masked partial sums over T ----------------
__global__ __launch_bounds__(256) void k_separt(const float* __restrict__ x,
                                                const int* __restrict__ mask,
                                                float* __restrict__ partial) {
    int b = blockIdx.x >> 5;
    int ch = blockIdx.x & 31;
    int t0 = ch * 64;
    int tid = threadIdx.x;
    int w4 = tid * 4;
    float4 acc = {0, 0, 0, 0};
    const float* xb = x + ((size_t)(b * Tdim + t0)) * Wdim + w4;
    const int* mb = mask + b * Tdim + t0;
    for (int i = 0; i < 64; i++) {
        if (!mb[i]) {
            float4 v = *(const float4*)(xb + (size_t)i * Wdim);
            acc.x += v.x; acc.y += v.y; acc.z += v.z; acc.w += v.w;
        }
    }
    *(float4*)(partial + ((size_t)(b * 32 + ch)) * Wdim + w4) = acc;
}

// ---------------- K4b: SE MLP + final projection -> out[b] ----------------
__global__ __launch_bounds__(256) void k_sefinal(const float* __restrict__ partial,
                                                 const int* __restrict__ mask,
                                                 const float* __restrict__ w1,
                                                 const float* __restrict__ b1,
                                                 const float* __restrict__ w2,
                                                 const float* __restrict__ b2,
                                                 const float* __restrict__ projw,
                                                 const float* __restrict__ projb,
                                                 float* __restrict__ out) {
    int b = blockIdx.x, tid = threadIdx.x;
    __shared__ float s[Wdim];
    __shared__ float hred[4][Hdim];
    __shared__ float hid[Hdim];
    __shared__ float rbuf[4];
    __shared__ float sLinv;
    int lane = tid & 63, wv = tid >> 6;

    // valid length
    int cnt = 0;
    for (int t = tid; t < Tdim; t += 256) cnt += (mask[b * Tdim + t] ? 0 : 1);
    float fc = (float)cnt;
#pragma unroll
    for (int off = 32; off > 0; off >>= 1) fc += __shfl_down(fc, off);
    if (lane == 0) rbuf[wv] = fc;
    __syncthreads();
    if (tid == 0) {
        float L = rbuf[0] + rbuf[1] + rbuf[2] + rbuf[3];
        sLinv = 1.f / fmaxf(L, 1.f);
    }
    __syncthreads();
    float Linv = sLinv;

    // s[w] = masked mean
    for (int w = tid; w < Wdim; w += 256) {
        float a = 0.f;
        for (int chh = 0; chh < 32; chh++) a += partial[((size_t)(b * 32 + chh)) * Wdim + w];
        s[w] = a * Linv;
    }
    __syncthreads();

    // hidden = relu(s @ w1 + b1)   (w1: [W][64])
    int j = tid & 63, p = tid >> 6;
    float ha = 0.f;
    for (int w = p * 256; w < (p + 1) * 256; ++w) ha += s[w] * w1[(size_t)w * Hdim + j];
    hred[p][j] = ha;
    __syncthreads();
    if (tid < Hdim)
        hid[tid] = fmaxf(hred[0][tid] + hred[1][tid] + hred[2][tid] + hred[3][tid] + b1[tid], 0.f);
    __syncthreads();

    // gate = sigmoid(hidden @ w2 + b2); out = sum_w s*gate*projw + projb
    float part = 0.f;
    for (int w = tid; w < Wdim; w += 256) {
        float ga = b2[w];
#pragma unroll 8
        for (int j2 = 0; j2 < Hdim; j2++) ga += hid[j2] * w2[(size_t)j2 * Wdim + w];
        float gate = 1.f / (1.f + expf(-ga));
        part += s[w] * gate * projw[w];
    }
#pragma unroll
    for (int off = 32; off > 0; off >>= 1) part += __shfl_down(part, off);
    __syncthreads();
    if (lane == 0) rbuf[wv] = part;
    __syncthreads();
    if (tid == 0) out[b] = rbuf[0] + rbuf[1] + rbuf[2] + rbuf[3] + projb[0];
}

extern "C" void kernel_launch(void* const* d_in, const int* in_sizes, int n_in,
                              void* d_out, int out_size, void* d_ws, size_t ws_size,
                              hipStream_t stream) {
    const float* h        = (const float*)d_in[0];
    const int*   mask     = (const int*)d_in[1];
    const float* offset_w = (const float*)d_in[2];
    const float* offset_b = (const float*)d_in[3];
    const float* conv_w   = (const float*)d_in[4];
    const float* conv_b   = (const float*)d_in[5];
    const float* ln_g     = (const float*)d_in[6];
    const float* ln_b     = (const float*)d_in[7];
    const float* se_w1    = (const float*)d_in[8];
    const float* se_b1    = (const float*)d_in[9];
    const float* se_w2    = (const float*)d_in[10];
    const float* se_b2    = (const float*)d_in[11];
    const float* proj_w   = (const float*)d_in[12];
    const float* proj_b   = (const float*)d_in[13];
    float* out = (float*)d_out;

    char* wsb = (char*)d_ws;
    int*   p0a     = (int*)(wsb);                    // 229,376 B
    float* fra     = (float*)(wsb + 229376);         // 229,376 B
    float* Wt      = (float*)(wsb + 458752);         // 3,670,016 B
    float* y       = (float*)(wsb + 4128768);        // 33,554,432 B
    float* partial = (float*)(wsb + 37683200);       // 524,288 B  (total ~38.2 MB)

    k_wt<<<dim3(3584), dim3(256), 0, stream>>>(conv_w, Wt);
    k_offsets<<<dim3(Bdim * Tdim), dim3(256), 0, stream>>>(h, offset_w, offset_b, p0a, fra);
    k_conv<<<dim3(Bdim * (Tdim / 16) * Gdim), dim3(256), 0, stream>>>(h, Wt, conv_b, p0a, fra, y);
    k_ln<<<dim3(Bdim * Tdim), dim3(256), 0, stream>>>(y, ln_g, ln_b);
    k_separt<<<dim3(Bdim * 32), dim3(256), 0, stream>>>(y, mask, partial);
    k_sefinal<<<dim3(Bdim), dim3(256), 0, stream>>>(partial, mask, se_w1, se_b1, se_w2, se_b2,
                                                    proj_w, proj_b, out);
}

// Round 3
// 130.768 us; speedup vs baseline: 4.1053x; 4.1053x over previous
//
#include <hip/hip_runtime.h>
#include <hip/hip_bf16.h>

#define Bdim 4
#define Tdim 2048
#define Wdim 1024
#define Kdim 7
#define Gdim 8
#define Cg   128
#define Hdim 64   // W / SE_R

typedef __attribute__((ext_vector_type(8))) short short8v;
typedef __attribute__((ext_vector_type(4))) float float4v;

__device__ __forceinline__ short f2bf(float x) {
    union { float f; unsigned u; } v; v.f = x;
    unsigned r = v.u + 0x7fff + ((v.u >> 16) & 1);   // RNE
    return (short)(r >> 16);
}

// ---------------- K0: conv_w [G][O][C][K] -> Wtb bf16 [G][K][o][c] pre-swizzled ----------------
// swizzle within each 256B row: byte ^= (o&7)<<4
__global__ __launch_bounds__(256) void k_wt(const float* __restrict__ conv_w,
                                            short* __restrict__ Wtb) {
    int i = blockIdx.x * 256 + threadIdx.x;
    if (i >= Gdim * Kdim * Cg * 16) return;     // 114688
    int cb = i & 15;
    int o = (i >> 4) & 127;
    int gk = i >> 11;                            // g*7 + k
    int k = gk % Kdim, g = gk / Kdim;
    const float* src = conv_w + ((size_t)(g * Cg + o) * Cg + cb * 8) * Kdim + k;
    short8v pk;
#pragma unroll
    for (int j = 0; j < 8; j++) pk[j] = f2bf(src[(size_t)j * Kdim]);
    char* row = (char*)(Wtb + (size_t)gk * (Cg * Cg) + (size_t)o * Cg);
    int byte = (cb * 16) ^ ((o & 7) << 4);
    *(short8v*)(row + byte) = pk;
}

// ---------------- K1: offsets = h @ offset_w + offset_b; -> p0, frac ----------------
__global__ __launch_bounds__(256) void k_offsets(const float* __restrict__ h,
                                                 const float* __restrict__ offset_w,
                                                 const float* __restrict__ offset_b,
                                                 int* __restrict__ p0a,
                                                 float* __restrict__ fra) {
    int bt = blockIdx.x;               // b*T + t
    int t = bt & (Tdim - 1);
    int tid = threadIdx.x;
    const float* row = h + (size_t)bt * Wdim;
    float4 hv = *(const float4*)(row + tid * 4);
    const float* ow = offset_w + (size_t)tid * 4 * Kdim;
    float acc[Kdim];
#pragma unroll
    for (int k = 0; k < Kdim; k++)
        acc[k] = hv.x * ow[k] + hv.y * ow[Kdim + k] + hv.z * ow[2 * Kdim + k] + hv.w * ow[3 * Kdim + k];

    __shared__ float wred[4][Kdim];
    int lane = tid & 63, wv = tid >> 6;
#pragma unroll
    for (int k = 0; k < Kdim; k++) {
        float v = acc[k];
#pragma unroll
        for (int off = 32; off > 0; off >>= 1) v += __shfl_down(v, off);
        if (lane == 0) wred[wv][k] = v;
    }
    __syncthreads();
    if (tid < Kdim) {
        float o = wred[0][tid] + wred[1][tid] + wred[2][tid] + wred[3][tid] + offset_b[tid];
        float base = (float)t + (float)(tid - 3);
        float pos = fminf(fmaxf(base + o, 0.f), (float)(Tdim - 1));
        float p0f = floorf(pos);
        p0a[bt * Kdim + tid] = (int)p0f;
        fra[bt * Kdim + tid] = pos - p0f;
    }
}

// ---------------- K2: deformable grouped conv via bf16 MFMA ----------------
// block = (b, 64-t tile, g); 256 threads = 4 waves; per-wave 16t x 128o
__global__ __launch_bounds__(256) void k_conv(const float* __restrict__ h,
                                              const short* __restrict__ Wtb,
                                              const float* __restrict__ conv_b,
                                              const int* __restrict__ p0a,
                                              const float* __restrict__ fra,
                                              float* __restrict__ y) {
    __shared__ __align__(16) short sA[64 * 128];    // 16 KB, XOR-swizzled rows
    __shared__ __align__(16) short sB[128 * 128];   // 32 KB, pre-swizzled in global

    int blk = blockIdx.x;              // (b*32 + tc)*8 + g
    int g = blk & 7;
    int tc = (blk >> 3) & 31;
    int b = blk >> 8;
    int t0 = tc * 64;
    int tid = threadIdx.x;
    int lane = tid & 63;
    int wv = tid >> 6;

    float4v acc[8];
#pragma unroll
    for (int n = 0; n < 8; n++) acc[n] = (float4v){0.f, 0.f, 0.f, 0.f};

    const float* hg = h + (size_t)b * Tdim * Wdim + g * Cg;
    const short* wg = Wtb + (size_t)g * Kdim * (Cg * Cg);

    for (int k = 0; k < Kdim; k++) {
        __syncthreads();
        // ---- stage A: 64t x 128c interp samples, 4 units of 8c per thread ----
#pragma unroll
        for (int i = 0; i < 4; i++) {
            int u = tid + i * 256;
            int r = u >> 4, cb = u & 15;
            int idx = (b * Tdim + t0 + r) * Kdim + k;
            int p0 = p0a[idx];
            float f = fra[idx];
            int p1 = min(p0 + 1, Tdim - 1);
            const float* s0p = hg + (size_t)p0 * Wdim + cb * 8;
            const float* s1p = hg + (size_t)p1 * Wdim + cb * 8;
            float4 a0 = *(const float4*)s0p;
            float4 a1 = *(const float4*)(s0p + 4);
            float4 b0 = *(const float4*)s1p;
            float4 b1 = *(const float4*)(s1p + 4);
            short8v pk;
            pk[0] = f2bf(a0.x + f * (b0.x - a0.x));
            pk[1] = f2bf(a0.y + f * (b0.y - a0.y));
            pk[2] = f2bf(a0.z + f * (b0.z - a0.z));
            pk[3] = f2bf(a0.w + f * (b0.w - a0.w));
            pk[4] = f2bf(a1.x + f * (b1.x - a1.x));
            pk[5] = f2bf(a1.y + f * (b1.y - a1.y));
            pk[6] = f2bf(a1.z + f * (b1.z - a1.z));
            pk[7] = f2bf(a1.w + f * (b1.w - a1.w));
            int off = r * 256 + ((cb * 16) ^ ((r & 7) << 4));
            *(short8v*)((char*)sA + off) = pk;
        }
        // ---- stage B: linear 32KB copy (already swizzled in global) ----
        const char* wk = (const char*)(wg + (size_t)k * (Cg * Cg));
#pragma unroll
        for (int i = 0; i < 8; i++) {
            int u = i * 256 + tid;
            *(float4*)((char*)sB + u * 16) = *(const float4*)(wk + u * 16);
        }
        __syncthreads();
        // ---- MFMA: 4 K-slices x 8 o-tiles ----
        int arow = (wv << 4) | (lane & 15);
#pragma unroll
        for (int kk = 0; kk < 4; kk++) {
            int kb = kk * 64 + (lane >> 4) * 16;
            short8v af = *(const short8v*)((const char*)sA + arow * 256 + (kb ^ ((arow & 7) << 4)));
#pragma unroll
            for (int n = 0; n < 8; n++) {
                int orow = n * 16 + (lane & 15);
                short8v bfv = *(const short8v*)((const char*)sB + orow * 256 + (kb ^ ((orow & 7) << 4)));
                acc[n] = __builtin_amdgcn_mfma_f32_16x16x32_bf16(af, bfv, acc[n], 0, 0, 0);
            }
        }
    }
    // ---- epilogue: D lane l reg j -> row (l>>4)*4+j, col l&15 ----
    int trow = t0 + (wv << 4) + ((lane >> 4) << 2);
    int ocol = lane & 15;
#pragma unroll
    for (int n = 0; n < 8; n++) {
        int o = n * 16 + ocol;
        float bias = conv_b[g * Cg + o];
        float* yp = y + ((size_t)(b * Tdim + trow)) * Wdim + g * Cg + o;
#pragma unroll
        for (int j = 0; j < 4; j++)
            yp[(size_t)j * Wdim] = acc[n][j] + bias;
    }
}

// ---------------- K3: LayerNorm in-place ----------------
__global__ __launch_bounds__(256) void k_ln(float* __restrict__ y,
                                            const float* __restrict__ ln_g,
                                            const float* __restrict__ ln_b) {
    int bt = blockIdx.x;
    float* row = y + (size_t)bt * Wdim;
    int tid = threadIdx.x;
    float4 v = *(const float4*)(row + tid * 4);
    float s = v.x + v.y + v.z + v.w;
    float q = v.x * v.x + v.y * v.y + v.z * v.z + v.w * v.w;
    __shared__ float rs[4], rq[4];
    __shared__ float mu_s, inv_s;
    int lane = tid & 63, wv = tid >> 6;
#pragma unroll
    for (int off = 32; off > 0; off >>= 1) { s += __shfl_down(s, off); q += __shfl_down(q, off); }
    if (lane == 0) { rs[wv] = s; rq[wv] = q; }
    __syncthreads();
    if (tid == 0) {
        float S = rs[0] + rs[1] + rs[2] + rs[3];
        float Q = rq[0] + rq[1] + rq[2] + rq[3];
        float mu = S * (1.f / Wdim);
        float var = Q * (1.f / Wdim) - mu * mu;
        mu_s = mu;
        inv_s = rsqrtf(var + 1e-5f);
    }
    __syncthreads();
    float mu = mu_s, inv = inv_s;
    float4 gg = *(const float4*)(ln_g + tid * 4);
    float4 bb = *(const float4*)(ln_b + tid * 4);
    v.x = (v.x - mu) * inv * gg.x + bb.x;
    v.y = (v.y - mu) * inv * gg.y + bb.y;
    v.z = (v.z - mu) * inv * gg.z + bb.z;
    v.w = (v.w - mu) * inv * gg.w + bb.w;
    *(float4*)(row + tid * 4) = v;
}

// ---------------- K4a: masked partial sums over T ----------------
__global__ __launch_bounds__(256) void k_separt(const float* __restrict__ x,
                                                const int* __restrict__ mask,
                                                float* __restrict__ partial) {
    int b = blockIdx.x >> 5;
    int ch = blockIdx.x & 31;
    int t0 = ch * 64;
    int tid = threadIdx.x;
    int w4 = tid * 4;
    float4 acc = {0, 0, 0, 0};
    const float* xb = x + ((size_t)(b * Tdim + t0)) * Wdim + w4;
    const int* mb = mask + b * Tdim + t0;
    for (int i = 0; i < 64; i++) {
        if (!mb[i]) {
            float4 v = *(const float4*)(xb + (size_t)i * Wdim);
            acc.x += v.x; acc.y += v.y; acc.z += v.z; acc.w += v.w;
        }
    }
    *(float4*)(partial + ((size_t)(b * 32 + ch)) * Wdim + w4) = acc;
}

// ---------------- K4b: SE MLP + final projection -> out[b] ----------------
__global__ __launch_bounds__(256) void k_sefinal(const float* __restrict__ partial,
                                                 const int* __restrict__ mask,
                                                 const float* __restrict__ w1,
                                                 const float* __restrict__ b1,
                                                 const float* __restrict__ w2,
                                                 const float* __restrict__ b2,
                                                 const float* __restrict__ projw,
                                                 const float* __restrict__ projb,
                                                 float* __restrict__ out) {
    int b = blockIdx.x, tid = threadIdx.x;
    __shared__ float s[Wdim];
    __shared__ float hred[4][Hdim];
    __shared__ float hid[Hdim];
    __shared__ float rbuf[4];
    __shared__ float sLinv;
    int lane = tid & 63, wv = tid >> 6;

    int cnt = 0;
    for (int t = tid; t < Tdim; t += 256) cnt += (mask[b * Tdim + t] ? 0 : 1);
    float fc = (float)cnt;
#pragma unroll
    for (int off = 32; off > 0; off >>= 1) fc += __shfl_down(fc, off);
    if (lane == 0) rbuf[wv] = fc;
    __syncthreads();
    if (tid == 0) {
        float L = rbuf[0] + rbuf[1] + rbuf[2] + rbuf[3];
        sLinv = 1.f / fmaxf(L, 1.f);
    }
    __syncthreads();
    float Linv = sLinv;

    for (int w = tid; w < Wdim; w += 256) {
        float a = 0.f;
        for (int chh = 0; chh < 32; chh++) a += partial[((size_t)(b * 32 + chh)) * Wdim + w];
        s[w] = a * Linv;
    }
    __syncthreads();

    int j = tid & 63, p = tid >> 6;
    float ha = 0.f;
    for (int w = p * 256; w < (p + 1) * 256; ++w) ha += s[w] * w1[(size_t)w * Hdim + j];
    hred[p][j] = ha;
    __syncthreads();
    if (tid < Hdim)
        hid[tid] = fmaxf(hred[0][tid] + hred[1][tid] + hred[2][tid] + hred[3][tid] + b1[tid], 0.f);
    __syncthreads();

    float part = 0.f;
    for (int w = tid; w < Wdim; w += 256) {
        float ga = b2[w];
#pragma unroll 8
        for (int j2 = 0; j2 < Hdim; j2++) ga += hid[j2] * w2[(size_t)j2 * Wdim + w];
        float gate = 1.f / (1.f + expf(-ga));
        part += s[w] * gate * projw[w];
    }
#pragma unroll
    for (int off = 32; off > 0; off >>= 1) part += __shfl_down(part, off);
    __syncthreads();
    if (lane == 0) rbuf[wv] = part;
    __syncthreads();
    if (tid == 0) out[b] = rbuf[0] + rbuf[1] + rbuf[2] + rbuf[3] + projb[0];
}

extern "C" void kernel_launch(void* const* d_in, const int* in_sizes, int n_in,
                              void* d_out, int out_size, void* d_ws, size_t ws_size,
                              hipStream_t stream) {
    const float* h        = (const float*)d_in[0];
    const int*   mask     = (const int*)d_in[1];
    const float* offset_w = (const float*)d_in[2];
    const float* offset_b = (const float*)d_in[3];
    const float* conv_w   = (const float*)d_in[4];
    const float* conv_b   = (const float*)d_in[5];
    const float* ln_g     = (const float*)d_in[6];
    const float* ln_b     = (const float*)d_in[7];
    const float* se_w1    = (const float*)d_in[8];
    const float* se_b1    = (const float*)d_in[9];
    const float* se_w2    = (const float*)d_in[10];
    const float* se_b2    = (const float*)d_in[11];
    const float* proj_w   = (const float*)d_in[12];
    const float* proj_b   = (const float*)d_in[13];
    float* out = (float*)d_out;

    char* wsb = (char*)d_ws;
    int*   p0a     = (int*)(wsb);                    //   229,376 B
    float* fra     = (float*)(wsb + 229376);         //   229,376 B
    short* Wtb     = (short*)(wsb + 458752);         // 1,835,008 B
    float* y       = (float*)(wsb + 2293760);        // 33,554,432 B
    float* partial = (float*)(wsb + 35848192);       //   524,288 B (total ~36.4 MB)

    k_wt<<<dim3(448), dim3(256), 0, stream>>>(conv_w, Wtb);
    k_offsets<<<dim3(Bdim * Tdim), dim3(256), 0, stream>>>(h, offset_w, offset_b, p0a, fra);
    k_conv<<<dim3(Bdim * (Tdim / 64) * Gdim), dim3(256), 0, stream>>>(h, Wtb, conv_b, p0a, fra, y);
    k_ln<<<dim3(Bdim * Tdim), dim3(256), 0, stream>>>(y, ln_g, ln_b);
    k_separt<<<dim3(Bdim * 32), dim3(256), 0, stream>>>(y, mask, partial);
    k_sefinal<<<dim3(Bdim), dim3(256), 0, stream>>>(partial, mask, se_w1, se_b1, se_w2, se_b2,
                                                    proj_w, proj_b, out);
}

// Round 4
// 115.832 us; speedup vs baseline: 4.6347x; 1.1289x over previous
//
#include <hip/hip_runtime.h>
#include <hip/hip_bf16.h>

#define Bdim 4
#define Tdim 2048
#define Wdim 1024
#define Kdim 7
#define Gdim 8
#define Cg   128
#define Hdim 64   // W / SE_R
#define TT   128  // t-rows per conv block

typedef __attribute__((ext_vector_type(8))) short short8v;
typedef __attribute__((ext_vector_type(4))) float float4v;

__device__ __forceinline__ short f2bf(float x) {
    union { float f; unsigned u; } v; v.f = x;
    unsigned r = v.u + 0x7fff + ((v.u >> 16) & 1);   // RNE
    return (short)(r >> 16);
}

// ---------------- K_pre: fused weight-transform + offsets ----------------
// blocks 0..447: conv_w [G][O][C][K] -> Wtb bf16 [G*K][o][unit], unit-swizzled (u = cb ^ (o&7))
// blocks 448.. : offsets = h @ offset_w + offset_b -> p0, frac
__global__ __launch_bounds__(256) void k_pre(const float* __restrict__ conv_w,
                                             short* __restrict__ Wtb,
                                             const float* __restrict__ h,
                                             const float* __restrict__ offset_w,
                                             const float* __restrict__ offset_b,
                                             int* __restrict__ p0a,
                                             float* __restrict__ fra) {
    int tid = threadIdx.x;
    if (blockIdx.x < 448) {
        int i = blockIdx.x * 256 + tid;
        if (i >= Gdim * Kdim * Cg * 16) return;     // 114688
        int cb = i & 15;
        int o = (i >> 4) & 127;
        int gk = i >> 11;                            // g*7 + k
        int k = gk % Kdim, g = gk / Kdim;
        const float* src = conv_w + ((size_t)(g * Cg + o) * Cg + cb * 8) * Kdim + k;
        short8v pk;
#pragma unroll
        for (int j = 0; j < 8; j++) pk[j] = f2bf(src[(size_t)j * Kdim]);
        short8v* Wtb8 = (short8v*)Wtb;
        Wtb8[(size_t)gk * 2048 + o * 16 + (cb ^ (o & 7))] = pk;
        return;
    }
    int bt = blockIdx.x - 448;         // b*T + t
    int t = bt & (Tdim - 1);
    const float* row = h + (size_t)bt * Wdim;
    float4 hv = *(const float4*)(row + tid * 4);
    const float* ow = offset_w + (size_t)tid * 4 * Kdim;
    float acc[Kdim];
#pragma unroll
    for (int k = 0; k < Kdim; k++)
        acc[k] = hv.x * ow[k] + hv.y * ow[Kdim + k] + hv.z * ow[2 * Kdim + k] + hv.w * ow[3 * Kdim + k];

    __shared__ float wred[4][Kdim];
    int lane = tid & 63, wv = tid >> 6;
#pragma unroll
    for (int k = 0; k < Kdim; k++) {
        float v = acc[k];
#pragma unroll
        for (int off = 32; off > 0; off >>= 1) v += __shfl_down(v, off);
        if (lane == 0) wred[wv][k] = v;
    }
    __syncthreads();
    if (tid < Kdim) {
        float o = wred[0][tid] + wred[1][tid] + wred[2][tid] + wred[3][tid] + offset_b[tid];
        float base = (float)t + (float)(tid - 3);
        float pos = fminf(fmaxf(base + o, 0.f), (float)(Tdim - 1));
        float p0f = floorf(pos);
        p0a[bt * Kdim + tid] = (int)p0f;
        fra[bt * Kdim + tid] = pos - p0f;
    }
}

// ---------------- K2: deformable grouped conv via bf16 MFMA ----------------
// 512 threads = 8 waves = 4 t-groups x 2 o-halves; wave covers 32t x 64o
__global__ __launch_bounds__(512) void k_conv(const float* __restrict__ h,
                                              const short* __restrict__ Wtb,
                                              const float* __restrict__ conv_b,
                                              const int* __restrict__ p0a,
                                              const float* __restrict__ fra,
                                              float* __restrict__ y) {
    __shared__ short8v sA8[TT * 16];     // 32 KB, unit-swizzled rows (256B each)
    __shared__ short8v sB8[Cg * 16];     // 32 KB, pre-swizzled in global

    int blk = blockIdx.x;                // (b*16 + tc)*8 + g
    int g = blk & 7;
    int tc = (blk >> 3) & 15;
    int b = blk >> 7;
    int t0 = tc * TT;
    int tid = threadIdx.x;
    int lane = tid & 63, wv = tid >> 6;
    int wt = wv & 3, wo = wv >> 2;
    int r15 = lane & 15, q = lane >> 4;
    int sw = r15 & 7;

    float4v acc[2][4];
#pragma unroll
    for (int tt = 0; tt < 2; tt++)
#pragma unroll
        for (int n = 0; n < 4; n++) acc[tt][n] = (float4v){0.f, 0.f, 0.f, 0.f};

    const float* hg = h + (size_t)b * Tdim * Wdim + g * Cg;
    const short8v* wgB = (const short8v*)Wtb + (size_t)(g * Kdim) * 2048;

    for (int k = 0; k < Kdim; k++) {
        __syncthreads();
        // ---- stage A: TT x 128c interp samples, 4 units of 8c per thread ----
#pragma unroll
        for (int i = 0; i < 4; i++) {
            int u = tid + i * 512;
            int r = u >> 4, cb = u & 15;
            int idx = (b * Tdim + t0 + r) * Kdim + k;
            int p0 = p0a[idx];
            float f = fra[idx];
            int p1 = min(p0 + 1, Tdim - 1);
            const float* s0p = hg + (size_t)p0 * Wdim + cb * 8;
            const float* s1p = hg + (size_t)p1 * Wdim + cb * 8;
            float4 a0 = *(const float4*)s0p;
            float4 a1 = *(const float4*)(s0p + 4);
            float4 b0 = *(const float4*)s1p;
            float4 b1 = *(const float4*)(s1p + 4);
            short8v pk;
            pk[0] = f2bf(a0.x + f * (b0.x - a0.x));
            pk[1] = f2bf(a0.y + f * (b0.y - a0.y));
            pk[2] = f2bf(a0.z + f * (b0.z - a0.z));
            pk[3] = f2bf(a0.w + f * (b0.w - a0.w));
            pk[4] = f2bf(a1.x + f * (b1.x - a1.x));
            pk[5] = f2bf(a1.y + f * (b1.y - a1.y));
            pk[6] = f2bf(a1.z + f * (b1.z - a1.z));
            pk[7] = f2bf(a1.w + f * (b1.w - a1.w));
            sA8[r * 16 + (cb ^ (r & 7))] = pk;
        }
        // ---- stage B: linear 32KB copy (already unit-swizzled in global) ----
        const short8v* wk = wgB + (size_t)k * 2048;
#pragma unroll
        for (int i = 0; i < 4; i++) {
            int u = tid + i * 512;
            sB8[u] = wk[u];
        }
        __syncthreads();
        // ---- MFMA: 4 K-slices; per wave 2 t-tiles x 4 o-tiles ----
#pragma unroll
        for (int kk = 0; kk < 4; kk++) {
            int cs = kk * 4 + q;
            short8v a0 = sA8[(wt * 32 + r15) * 16 + (cs ^ sw)];
            short8v a1 = sA8[(wt * 32 + 16 + r15) * 16 + (cs ^ sw)];
#pragma unroll
            for (int n = 0; n < 4; n++) {
                int orow = wo * 64 + n * 16 + r15;
                short8v bfv = sB8[orow * 16 + (cs ^ sw)];
                acc[0][n] = __builtin_amdgcn_mfma_f32_16x16x32_bf16(a0, bfv, acc[0][n], 0, 0, 0);
                acc[1][n] = __builtin_amdgcn_mfma_f32_16x16x32_bf16(a1, bfv, acc[1][n], 0, 0, 0);
            }
        }
    }
    // ---- epilogue: D lane l reg j -> row (l>>4)*4+j, col l&15 ----
    int trow0 = t0 + wt * 32 + q * 4;
#pragma unroll
    for (int n = 0; n < 4; n++) {
        int o = wo * 64 + n * 16 + r15;
        float bias = conv_b[g * Cg + o];
#pragma unroll
        for (int tt = 0; tt < 2; tt++) {
            float* yp = y + ((size_t)(b * Tdim + trow0 + tt * 16)) * Wdim + g * Cg + o;
#pragma unroll
            for (int j = 0; j < 4; j++)
                yp[(size_t)j * Wdim] = acc[tt][n][j] + bias;
        }
    }
}

// ---------------- K3: fused LayerNorm + masked pool partials ----------------
// block = (b, 16-row chunk); accumulates sum of (v-mu)*rsig over valid rows
__global__ __launch_bounds__(256) void k_lnpool(const float* __restrict__ y,
                                                const int* __restrict__ mask,
                                                float* __restrict__ partial) {
    int bc = blockIdx.x;
    int b = bc >> 7, ch = bc & 127;
    int t0 = ch * 16;
    int tid = threadIdx.x;
    int lane = tid & 63, wv = tid >> 6;
    __shared__ float rs[4], rq[4];
    __shared__ float smu, sinv;
    float4 acc = {0, 0, 0, 0};
    for (int i = 0; i < 16; i++) {
        int t = t0 + i;
        if (mask[b * Tdim + t]) continue;
        float4 v = *(const float4*)(y + (size_t)(b * Tdim + t) * Wdim + tid * 4);
        float s = v.x + v.y + v.z + v.w;
        float qq = v.x * v.x + v.y * v.y + v.z * v.z + v.w * v.w;
#pragma unroll
        for (int off = 32; off > 0; off >>= 1) { s += __shfl_down(s, off); qq += __shfl_down(qq, off); }
        if (lane == 0) { rs[wv] = s; rq[wv] = qq; }
        __syncthreads();
        if (tid == 0) {
            float S = rs[0] + rs[1] + rs[2] + rs[3];
            float Q = rq[0] + rq[1] + rq[2] + rq[3];
            float mu = S * (1.f / Wdim);
            smu = mu;
            sinv = rsqrtf(Q * (1.f / Wdim) - mu * mu + 1e-5f);
        }
        __syncthreads();
        float mu = smu, inv = sinv;
        acc.x += (v.x - mu) * inv;
        acc.y += (v.y - mu) * inv;
        acc.z += (v.z - mu) * inv;
        acc.w += (v.w - mu) * inv;
    }
    *(float4*)(partial + (size_t)bc * Wdim + tid * 4) = acc;
}

// ---------------- K4: SE MLP + final projection -> out[b] ----------------
__global__ __launch_bounds__(256) void k_sefinal(const float* __restrict__ partial,
                                                 const int* __restrict__ mask,
                                                 const float* __restrict__ ln_g,
                                                 const float* __restrict__ ln_b,
                                                 const float* __restrict__ w1,
                                                 const float* __restrict__ b1,
                                                 const float* __restrict__ w2,
                                                 const float* __restrict__ b2,
                                                 const float* __restrict__ projw,
                                                 const float* __restrict__ projb,
                                                 float* __restrict__ out) {
    int b = blockIdx.x, tid = threadIdx.x;
    __shared__ float s[Wdim];
    __shared__ float hred[4][Hdim];
    __shared__ float hid[Hdim];
    __shared__ float rbuf[4];
    __shared__ float sLinv;
    int lane = tid & 63, wv = tid >> 6;

    int cnt = 0;
    for (int t = tid; t < Tdim; t += 256) cnt += (mask[b * Tdim + t] ? 0 : 1);
    float fc = (float)cnt;
#pragma unroll
    for (int off = 32; off > 0; off >>= 1) fc += __shfl_down(fc, off);
    if (lane == 0) rbuf[wv] = fc;
    __syncthreads();
    if (tid == 0) {
        float L = rbuf[0] + rbuf[1] + rbuf[2] + rbuf[3];
        sLinv = 1.f / fmaxf(L, 1.f);
    }
    __syncthreads();
    float Linv = sLinv;

    // s[w] = ln_g * (sum/L) + ln_b
    int w4 = tid * 4;
    float4 a = {0, 0, 0, 0};
    for (int chh = 0; chh < 128; chh++) {
        float4 p = *(const float4*)(partial + ((size_t)(b * 128 + chh)) * Wdim + w4);
        a.x += p.x; a.y += p.y; a.z += p.z; a.w += p.w;
    }
    float4 gg = *(const float4*)(ln_g + w4);
    float4 bb = *(const float4*)(ln_b + w4);
    s[w4 + 0] = gg.x * (a.x * Linv) + bb.x;
    s[w4 + 1] = gg.y * (a.y * Linv) + bb.y;
    s[w4 + 2] = gg.z * (a.z * Linv) + bb.z;
    s[w4 + 3] = gg.w * (a.w * Linv) + bb.w;
    __syncthreads();

    int j = tid & 63, p = tid >> 6;
    float ha = 0.f;
    for (int w = p * 256; w < (p + 1) * 256; ++w) ha += s[w] * w1[(size_t)w * Hdim + j];
    hred[p][j] = ha;
    __syncthreads();
    if (tid < Hdim)
        hid[tid] = fmaxf(hred[0][tid] + hred[1][tid] + hred[2][tid] + hred[3][tid] + b1[tid], 0.f);
    __syncthreads();

    float part = 0.f;
    for (int w = tid; w < Wdim; w += 256) {
        float ga = b2[w];
#pragma unroll 8
        for (int j2 = 0; j2 < Hdim; j2++) ga += hid[j2] * w2[(size_t)j2 * Wdim + w];
        float gate = 1.f / (1.f + expf(-ga));
        part += s[w] * gate * projw[w];
    }
#pragma unroll
    for (int off = 32; off > 0; off >>= 1) part += __shfl_down(part, off);
    __syncthreads();
    if (lane == 0) rbuf[wv] = part;
    __syncthreads();
    if (tid == 0) out[b] = rbuf[0] + rbuf[1] + rbuf[2] + rbuf[3] + projb[0];
}

extern "C" void kernel_launch(void* const* d_in, const int* in_sizes, int n_in,
                              void* d_out, int out_size, void* d_ws, size_t ws_size,
                              hipStream_t stream) {
    const float* h        = (const float*)d_in[0];
    const int*   mask     = (const int*)d_in[1];
    const float* offset_w = (const float*)d_in[2];
    const float* offset_b = (const float*)d_in[3];
    const float* conv_w   = (const float*)d_in[4];
    const float* conv_b   = (const float*)d_in[5];
    const float* ln_g     = (const float*)d_in[6];
    const float* ln_b     = (const float*)d_in[7];
    const float* se_w1    = (const float*)d_in[8];
    const float* se_b1    = (const float*)d_in[9];
    const float* se_w2    = (const float*)d_in[10];
    const float* se_b2    = (const float*)d_in[11];
    const float* proj_w   = (const float*)d_in[12];
    const float* proj_b   = (const float*)d_in[13];
    float* out = (float*)d_out;

    char* wsb = (char*)d_ws;
    int*   p0a     = (int*)(wsb);                    //   229,376 B
    float* fra     = (float*)(wsb + 229376);         //   229,376 B
    short* Wtb     = (short*)(wsb + 458752);         // 1,835,008 B
    float* y       = (float*)(wsb + 2293760);        // 33,554,432 B
    float* partial = (float*)(wsb + 35848192);       // 2,097,152 B (total ~36.2 MB)

    k_pre<<<dim3(448 + Bdim * Tdim), dim3(256), 0, stream>>>(conv_w, Wtb, h, offset_w, offset_b,
                                                             p0a, fra);
    k_conv<<<dim3(Bdim * (Tdim / TT) * Gdim), dim3(512), 0, stream>>>(h, Wtb, conv_b, p0a, fra, y);
    k_lnpool<<<dim3(Bdim * 128), dim3(256), 0, stream>>>(y, mask, partial);
    k_sefinal<<<dim3(Bdim), dim3(256), 0, stream>>>(partial, mask, ln_g, ln_b,
                                                    se_w1, se_b1, se_w2, se_b2,
                                                    proj_w, proj_b, out);
}